// Round 1
// baseline (9957.321 us; speedup 1.0000x reference)
//
#include <hip/hip_runtime.h>

// ---------------- types / helpers ----------------
typedef short bf8_t __attribute__((ext_vector_type(8)));   // 8 x bf16
typedef float f4_t  __attribute__((ext_vector_type(4)));

__device__ __forceinline__ f4_t mfma_bf16(bf8_t a, bf8_t b, f4_t c){
    return __builtin_amdgcn_mfma_f32_16x16x32_bf16(a, b, c, 0, 0, 0);
}
__device__ __forceinline__ unsigned short f2bf(float f){
    unsigned u = __float_as_uint(f);
    unsigned r = (u + 0x7FFFu + ((u >> 16) & 1u)) >> 16;
    return (unsigned short)r;
}
__device__ __forceinline__ float bf2f(unsigned short b){
    return __uint_as_float(((unsigned)b) << 16);
}
__device__ __forceinline__ void splitbf(float v, unsigned short& hi, unsigned short& lo){
    hi = f2bf(v);
    lo = f2bf(v - bf2f(hi));
}
__device__ __forceinline__ float sigm(float x){ return 1.0f / (1.0f + expf(-x)); }

// ---------------- problem sizes ----------------
#define SB   16      // batch
#define SS_  512     // seq
#define SH   512     // hidden
#define SE   256     // emb
#define SV   8192    // vocab
#define NBLK_REC 96  // 16 F + 48 proj + 32 gates

// ---------------- workspace layout (bytes) ----------------
#define OFF_XE_HI   ((size_t)0)
#define OFF_XE_LO   ((size_t)4194304)
#define OFF_WIH_HI  ((size_t)8388608)
#define OFF_WIH_LO  ((size_t)9437184)
#define OFF_WHH_HI  ((size_t)10485760)
#define OFF_WHH_LO  ((size_t)12582912)
#define OFF_WOUT    ((size_t)14680064)
#define OFF_XPROJ   ((size_t)23068672)
#define OFF_OUTSBF  ((size_t)90177536)
#define OFF_HBUF    ((size_t)98566144)   // zero region starts here
#define OFF_HBUFHI  ((size_t)98631680)
#define OFF_HBUFLO  ((size_t)98664448)
#define OFF_CBUF    ((size_t)98697216)
#define OFF_ZBUF    ((size_t)98729984)
#define OFF_PBUF    ((size_t)98828288)
#define OFF_BAR     ((size_t)98850816)
#define ZERO_WORDS  71232                // (98851072 - 98566144)/4

// ---------------- prep: conversions + gather + zero ----------------
#define N_WHH  1048576
#define N_WIH  524288
#define N_WOUT 4194304
#define N_XE   2097152
#define N_PREP (N_WHH + N_WIH + N_WOUT + N_XE + ZERO_WORDS)

__global__ __launch_bounds__(256) void k_prep(
    const int* __restrict__ x, const float* __restrict__ emb,
    const float* __restrict__ W_ih, const float* __restrict__ W_hh,
    const float* __restrict__ W_out,
    unsigned short* __restrict__ xe_hi, unsigned short* __restrict__ xe_lo,
    unsigned short* __restrict__ wih_hi, unsigned short* __restrict__ wih_lo,
    unsigned short* __restrict__ whh_hi, unsigned short* __restrict__ whh_lo,
    unsigned short* __restrict__ wout_bf, unsigned* __restrict__ zero_base)
{
    for (long i = (long)blockIdx.x * 256 + threadIdx.x; i < N_PREP; i += (long)gridDim.x * 256){
        long j = i;
        if (j < N_WHH){
            unsigned short h, l; splitbf(W_hh[j], h, l); whh_hi[j] = h; whh_lo[j] = l; continue;
        }
        j -= N_WHH;
        if (j < N_WIH){
            unsigned short h, l; splitbf(W_ih[j], h, l); wih_hi[j] = h; wih_lo[j] = l; continue;
        }
        j -= N_WIH;
        if (j < N_WOUT){ wout_bf[j] = f2bf(W_out[j]); continue; }
        j -= N_WOUT;
        if (j < N_XE){
            int r = (int)(j >> 8), e = (int)(j & 255);
            int t = r >> 4, b = r & 15;
            int tok = x[b * SS_ + t];
            unsigned short h, l; splitbf(emb[(size_t)tok * SE + e], h, l);
            xe_hi[j] = h; xe_lo[j] = l; continue;
        }
        j -= N_XE;
        zero_base[j] = 0u;
    }
}

// ---------------- xproj GEMM: C[8192][2048] = xe(hi/lo) @ W_ih(hi/lo)^T + b ----------------
__global__ __launch_bounds__(256) void k_xproj(
    const unsigned short* __restrict__ Ah, const unsigned short* __restrict__ Al,
    const unsigned short* __restrict__ Bh, const unsigned short* __restrict__ Bl,
    const float* __restrict__ bias, float* __restrict__ C)
{
    constexpr int K = 256, N = 2048;
    __shared__ unsigned short sA0[128*32], sA1[128*32], sB0[128*32], sB1[128*32];
    const int tid = threadIdx.x;
    const int m0 = blockIdx.y * 128, n0 = blockIdx.x * 128;
    const int lane = tid & 63, wid = tid >> 6;
    const int lm = lane & 15, lq = lane >> 4;
    const int wm = wid & 1, wn = wid >> 1;
    f4_t zero4 = {0.f, 0.f, 0.f, 0.f};
    f4_t acc[4][4];
    #pragma unroll
    for (int i = 0; i < 4; ++i)
        #pragma unroll
        for (int j = 0; j < 4; ++j) acc[i][j] = zero4;
    const int srow = tid >> 2, sq = tid & 3;
    for (int kk = 0; kk < K; kk += 32){
        __syncthreads();
        #pragma unroll
        for (int r2 = 0; r2 < 2; ++r2){
            int row = r2 * 64 + srow;
            int cell = (((row >> 4) << 2) + sq) * 16 + (row & 15);
            *(bf8_t*)&sA0[cell*8] = *(const bf8_t*)&Ah[(size_t)(m0+row)*K + kk + sq*8];
            *(bf8_t*)&sA1[cell*8] = *(const bf8_t*)&Al[(size_t)(m0+row)*K + kk + sq*8];
            *(bf8_t*)&sB0[cell*8] = *(const bf8_t*)&Bh[(size_t)(n0+row)*K + kk + sq*8];
            *(bf8_t*)&sB1[cell*8] = *(const bf8_t*)&Bl[(size_t)(n0+row)*K + kk + sq*8];
        }
        __syncthreads();
        bf8_t ah[4], al[4], bh[4], bl[4];
        #pragma unroll
        for (int i = 0; i < 4; ++i){
            int ca = (((wm*4 + i)*4 + lq)*16 + lm)*8;
            ah[i] = *(bf8_t*)&sA0[ca]; al[i] = *(bf8_t*)&sA1[ca];
            int cb = (((wn*4 + i)*4 + lq)*16 + lm)*8;
            bh[i] = *(bf8_t*)&sB0[cb]; bl[i] = *(bf8_t*)&sB1[cb];
        }
        #pragma unroll
        for (int i = 0; i < 4; ++i)
            #pragma unroll
            for (int j = 0; j < 4; ++j){
                acc[i][j] = mfma_bf16(ah[i], bh[j], acc[i][j]);
                acc[i][j] = mfma_bf16(ah[i], bl[j], acc[i][j]);
                acc[i][j] = mfma_bf16(al[i], bh[j], acc[i][j]);
            }
    }
    #pragma unroll
    for (int i = 0; i < 4; ++i)
        #pragma unroll
        for (int j = 0; j < 4; ++j){
            int mg = m0 + (wm*4 + i)*16 + lq*4;
            int ng = n0 + (wn*4 + j)*16 + lm;
            float bn = bias[ng];
            #pragma unroll
            for (int r = 0; r < 4; ++r)
                C[(size_t)(mg + r)*N + ng] = acc[i][j][r] + bn;
        }
}

// ---------------- logits GEMM: C[8192][8192] = outs_bf @ wout_bf^T ----------------
__global__ __launch_bounds__(256) void k_logits(
    const unsigned short* __restrict__ A, const unsigned short* __restrict__ B,
    float* __restrict__ C)
{
    constexpr int K = 512, N = 8192;
    __shared__ unsigned short sA[128*32], sB[128*32];
    const int tid = threadIdx.x;
    const int m0 = blockIdx.y * 128, n0 = blockIdx.x * 128;
    const int lane = tid & 63, wid = tid >> 6;
    const int lm = lane & 15, lq = lane >> 4;
    const int wm = wid & 1, wn = wid >> 1;
    f4_t zero4 = {0.f, 0.f, 0.f, 0.f};
    f4_t acc[4][4];
    #pragma unroll
    for (int i = 0; i < 4; ++i)
        #pragma unroll
        for (int j = 0; j < 4; ++j) acc[i][j] = zero4;
    const int srow = tid >> 2, sq = tid & 3;
    for (int kk = 0; kk < K; kk += 32){
        __syncthreads();
        #pragma unroll
        for (int r2 = 0; r2 < 2; ++r2){
            int row = r2 * 64 + srow;
            int cell = (((row >> 4) << 2) + sq) * 16 + (row & 15);
            *(bf8_t*)&sA[cell*8] = *(const bf8_t*)&A[(size_t)(m0+row)*K + kk + sq*8];
            *(bf8_t*)&sB[cell*8] = *(const bf8_t*)&B[(size_t)(n0+row)*K + kk + sq*8];
        }
        __syncthreads();
        bf8_t af[4], bfv[4];
        #pragma unroll
        for (int i = 0; i < 4; ++i){
            af[i]  = *(bf8_t*)&sA[(((wm*4 + i)*4 + lq)*16 + lm)*8];
            bfv[i] = *(bf8_t*)&sB[(((wn*4 + i)*4 + lq)*16 + lm)*8];
        }
        #pragma unroll
        for (int i = 0; i < 4; ++i)
            #pragma unroll
            for (int j = 0; j < 4; ++j)
                acc[i][j] = mfma_bf16(af[i], bfv[j], acc[i][j]);
    }
    #pragma unroll
    for (int i = 0; i < 4; ++i)
        #pragma unroll
        for (int j = 0; j < 4; ++j){
            int mg = m0 + (wm*4 + i)*16 + lq*4;
            int ng = n0 + (wn*4 + j)*16 + lm;
            #pragma unroll
            for (int r = 0; r < 4; ++r)
                C[(size_t)(mg + r)*N + ng] = acc[i][j][r];
        }
}

// ---------------- persistent recurrent kernel ----------------
struct RecP {
    const float* xproj;
    const unsigned short* whh_hi; const unsigned short* whh_lo;
    const int* x;
    const float* W_write; const float* b_write;
    const float* W_read;  const float* b_read;
    const float* W_lin;   const float* b_lin;
    unsigned short* outs_bf;
    float* hbuf; unsigned short* hbuf_hi; unsigned short* hbuf_lo;
    float* cbuf; float* zbuf; float* pbuf;
    unsigned* bar;
    float* fraw_out;
};

__device__ __forceinline__ void gbar(unsigned* bar, unsigned epoch){
    __syncthreads();
    if (threadIdx.x == 0){
        __threadfence();
        unsigned pos = __hip_atomic_fetch_add(&bar[0], 1u, __ATOMIC_ACQ_REL, __HIP_MEMORY_SCOPE_AGENT);
        if (pos == NBLK_REC - 1){
            __hip_atomic_store(&bar[0], 0u, __ATOMIC_RELAXED, __HIP_MEMORY_SCOPE_AGENT);
            __hip_atomic_store(&bar[1], epoch, __ATOMIC_RELEASE, __HIP_MEMORY_SCOPE_AGENT);
        } else {
            while (__hip_atomic_load(&bar[1], __ATOMIC_ACQUIRE, __HIP_MEMORY_SCOPE_AGENT) < epoch)
                __builtin_amdgcn_s_sleep(2);
        }
        __threadfence();
    }
    __syncthreads();
}

// shared-mem float offsets (union across roles)
// F: wsr@0[1024] qrr@1024[1024] scr@2048[1152] sv@3200 rv@3232 tv@3264 qv@3296
//    rrv@3328 nvg@3360 qn@3392 red@3424[8] msc@3432[8]
// proj: zt(cells)@0[8192] wlds@8192[4*516] scratch@10256[256] bias@10512[4]
// gates: gsc@0[4*16*17]
__global__ void __launch_bounds__(256, 1) k_rec(RecP P)
{
    __shared__ __align__(16) float smem[10528];
    const int tid = threadIdx.x, bid = blockIdx.x;
    const int lane = tid & 63, wv = tid >> 6;
    const int lm = lane & 15, lq = lane >> 4;
    f4_t zero4 = {0.f, 0.f, 0.f, 0.f};

    f4_t Freg[32];
    #pragma unroll
    for (int i = 0; i < 32; ++i) Freg[i] = zero4;

    // one-time per-block init
    if (bid < 16){
        if (tid == 0) smem[3432] = 1.0f;         // g scalar
    } else if (bid < 64){
        int pj = bid - 16;
        for (int i = tid; i < 4*512; i += 256){
            int rl = i >> 9, k = i & 511;
            int jr = pj*4 + rl;
            float v = 0.f;
            if (jr < 97) v = P.W_write[jr*512 + k];
            else if (jr < 161) v = P.W_read[(jr-97)*512 + k];
            smem[8192 + rl*516 + k] = v;
        }
        if (tid < 4){
            int jr = pj*4 + tid;
            float v = 0.f;
            if (jr < 97) v = P.b_write[jr];
            else if (jr < 161) v = P.b_read[jr-97];
            smem[10512 + tid] = v;
        }
    }
    __syncthreads();

    for (int w = 0; w < SS_ + 2; ++w){
        if (bid < 16){
            // ---------------- F block: batch b, step wf = w-2 ----------------
            if (w >= 2){
                const int b = bid, wf = w - 2;
                float* wsr = smem;        float* qrr = smem + 1024;
                float* scr = smem + 2048; float* sv  = smem + 3200;
                float* rv_ = smem + 3232; float* tv  = smem + 3264;
                float* qv_ = smem + 3296; float* rrv = smem + 3328;
                float* nvg = smem + 3360; float* qn  = smem + 3392;
                float* red = smem + 3424; float* msc = smem + 3432;
                const float* prow = P.pbuf + (size_t)(wf & 1)*(16*176) + b*176;
                if (tid < 161){
                    float val = prow[tid];
                    if (tid < 32) sv[tid] = val;
                    else if (tid < 64) rv_[tid-32] = val;
                    else if (tid < 96) tv[tid-64] = val;
                    else if (tid < 128) qv_[tid-96] = val;
                    else if (tid < 160) rrv[tid-128] = val;
                    else msc[1] = val;                         // beta
                }
                if (tid == 161) msc[3] = (P.x[b*SS_ + wf] == 0) ? 1.0f : 0.0f;
                __syncthreads();
                #pragma unroll
                for (int p = tid; p < 1024; p += 256){
                    int si = p >> 5, ri = p & 31;
                    wsr[p] = sv[si] * rv_[ri];
                    qrr[p] = qv_[si] * rrv[ri];
                }
                __syncthreads();
                const int tsg = lane & 7, p0 = lane >> 3;
                const int pb = wv*256 + p0;
                // pass A: v einsum
                f4_t vacc = zero4;
                #pragma unroll
                for (int it = 0; it < 32; ++it)
                    vacc += Freg[it] * wsr[pb + it*8];
                *(f4_t*)&scr[(wv*8 + p0)*36 + tsg*4] = vacc;
                __syncthreads();
                float gcur = msc[0];
                float beta = msc[1];
                if (tid < 32){
                    float ve = 0.f;
                    #pragma unroll
                    for (int r = 0; r < 32; ++r) ve += scr[r*36 + tid];
                    float nv = beta * (tv[tid] - gcur * ve) * (1.0f/32.0f);
                    nvg[tid] = nv / gcur;
                }
                __syncthreads();
                // pass B: fn, norm acc, q acc, F update
                f4_t nv4 = *(const f4_t*)&nvg[tsg*4];
                bool upd = (msc[3] == 0.0f);
                float nacc = 0.f; f4_t qacc = zero4;
                #pragma unroll
                for (int it = 0; it < 32; ++it){
                    int p = pb + it*8;
                    f4_t fn = Freg[it] + wsr[p] * nv4;
                    nacc += fn[0]*fn[0] + fn[1]*fn[1] + fn[2]*fn[2] + fn[3]*fn[3];
                    qacc += fn * qrr[p];
                    if (upd) Freg[it] = fn;
                }
                *(f4_t*)&scr[(wv*8 + p0)*36 + tsg*4] = qacc;
                #pragma unroll
                for (int off = 32; off > 0; off >>= 1) nacc += __shfl_down(nacc, off);
                if (lane == 0) red[wv] = nacc;
                __syncthreads();
                if (tid == 0){
                    float tot = red[0] + red[1] + red[2] + red[3];
                    float fraw = gcur * sqrtf(tot);
                    msc[2] = fraw;
                    float ex = fraw - 1.0f; if (ex < 0.f) ex = 0.f;
                    if (upd) msc[0] = gcur / (ex + 1.0f);
                }
                __syncthreads();
                if (tid < 32){
                    float q_ = 0.f;
                    #pragma unroll
                    for (int r = 0; r < 32; ++r) q_ += scr[r*36 + tid];
                    float mu = q_;
                    mu += __shfl_xor(mu, 1);  mu += __shfl_xor(mu, 2);
                    mu += __shfl_xor(mu, 4);  mu += __shfl_xor(mu, 8);
                    mu += __shfl_xor(mu, 16); mu *= (1.0f/32.0f);
                    float d = q_ - mu;
                    float vvr = d * d;
                    vvr += __shfl_xor(vvr, 1);  vvr += __shfl_xor(vvr, 2);
                    vvr += __shfl_xor(vvr, 4);  vvr += __shfl_xor(vvr, 8);
                    vvr += __shfl_xor(vvr, 16); vvr *= (1.0f/32.0f);
                    qn[tid] = d / sqrtf(vvr + 1e-5f);
                }
                __syncthreads();
                const float* zrow = P.zbuf + (size_t)(wf % 3)*8192 + b*512;
                f4_t qn4[8];
                #pragma unroll
                for (int i = 0; i < 8; ++i) qn4[i] = ((const f4_t*)qn)[i];
                for (int h = tid; h < 512; h += 256){
                    const float* wl = P.W_lin + h*32;
                    float o = P.b_lin[h] + zrow[h];
                    #pragma unroll
                    for (int i = 0; i < 8; ++i){
                        f4_t w4 = *(const f4_t*)&wl[i*4 + 0];
                        o += w4[0]*qn4[i][0] + w4[1]*qn4[i][1] + w4[2]*qn4[i][2] + w4[3]*qn4[i][3];
                    }
                    P.outs_bf[(size_t)(b*SS_ + wf)*SH + h] = f2bf(o);
                }
                if (wf == SS_ - 1 && tid == 0) P.fraw_out[b] = msc[2];
            }
        } else if (bid < 64){
            // ---------------- proj block: rows pj*4..+3, step wp = w-1 ----------------
            if (w >= 1 && w <= SS_){
                const int pj = bid - 16, wp = w - 1;
                const float* zsrc = P.zbuf + (size_t)(wp % 3)*8192;
                for (int c = tid; c < 2048; c += 256){
                    int i = c >> 6, bb = (c >> 2) & 15, hf = c & 3;
                    ((f4_t*)smem)[c] = *(const f4_t*)&zsrc[bb*512 + (hf + 4*i)*4];
                }
                __syncthreads();
                {
                    int rl = tid >> 6, bb = (tid >> 2) & 15, hf = tid & 3;
                    float acc = 0.f;
                    #pragma unroll 4
                    for (int i = 0; i < 32; ++i){
                        f4_t z4 = ((f4_t*)smem)[i*64 + bb*4 + hf];
                        f4_t w4 = *(f4_t*)&smem[8192 + rl*516 + (hf + 4*i)*4];
                        acc += z4[0]*w4[0] + z4[1]*w4[1] + z4[2]*w4[2] + z4[3]*w4[3];
                    }
                    smem[10256 + tid] = acc;
                }
                __syncthreads();
                if (tid < 64){
                    int rl = tid >> 4, bb = tid & 15;
                    int base = 10256 + rl*64 + bb*4;
                    float v = smem[base] + smem[base+1] + smem[base+2] + smem[base+3]
                            + smem[10512 + rl];
                    int jr = pj*4 + rl;
                    float* pbrow = P.pbuf + (size_t)(wp & 1)*(16*176) + bb*176;
                    if (jr < 32)        pbrow[jr] = tanhf(v);
                    else if (jr < 64)   pbrow[jr] = tanhf(v);
                    else if (jr < 96)   pbrow[jr] = tanhf(v);
                    else if (jr == 96)  pbrow[160] = sigm(v + 1.0f);
                    else if (jr < 129)  pbrow[96 + (jr - 97)] = v;
                    else if (jr < 161)  pbrow[128 + (jr - 129)] = tanhf(v);
                }
                __syncthreads();
            }
        } else {
            // ---------------- gates block: h0..h0+15, step w ----------------
            if (w < SS_){
                const int h0 = (bid - 64) * 16;
                const int parity = w & 1;
                const int g = wv;   // wave = gate
                const unsigned short* ah = P.hbuf_hi + (size_t)parity*8192 + lm*512;
                const unsigned short* al = P.hbuf_lo + (size_t)parity*8192 + lm*512;
                const unsigned short* bh = P.whh_hi + (size_t)(g*512 + h0 + lm)*512;
                const unsigned short* bl = P.whh_lo + (size_t)(g*512 + h0 + lm)*512;
                float xp[4];
                #pragma unroll
                for (int r = 0; r < 4; ++r){
                    int m = lq*4 + r;
                    xp[r] = P.xproj[(size_t)(w*16 + m)*2048 + g*512 + h0 + lm];
                }
                f4_t accs[4];
                #pragma unroll
                for (int i = 0; i < 4; ++i) accs[i] = zero4;
                #pragma unroll
                for (int kc = 0; kc < 16; ++kc){
                    int k = kc*32 + lq*8;
                    bf8_t vah = *(const bf8_t*)(ah + k);
                    bf8_t val_ = *(const bf8_t*)(al + k);
                    bf8_t vbh = *(const bf8_t*)(bh + k);
                    bf8_t vbl = *(const bf8_t*)(bl + k);
                    accs[kc & 3] = mfma_bf16(vah, vbh, accs[kc & 3]);
                    accs[kc & 3] = mfma_bf16(vah, vbl, accs[kc & 3]);
                    accs[kc & 3] = mfma_bf16(val_, vbh, accs[kc & 3]);
                }
                f4_t s4 = accs[0] + accs[1] + accs[2] + accs[3];
                #pragma unroll
                for (int r = 0; r < 4; ++r){
                    int m = lq*4 + r;
                    smem[(g*16 + m)*17 + lm] = s4[r] + xp[r];
                }
                __syncthreads();
                {
                    int bb = tid >> 4, hh = tid & 15, h = h0 + hh;
                    float iv = smem[(0*16 + bb)*17 + hh];
                    float fv = smem[(1*16 + bb)*17 + hh];
                    float zg = smem[(2*16 + bb)*17 + hh];
                    float ov = smem[(3*16 + bb)*17 + hh];
                    iv = sigm(iv); fv = sigm(fv + 1.0f); zg = tanhf(zg); ov = sigm(ov);
                    int cidx = bb*512 + h;
                    float c_old = P.cbuf[cidx];
                    float nc = fv * c_old + iv * zg;
                    float nh = ov * tanhf(nc);
                    P.zbuf[(size_t)(w % 3)*8192 + cidx] = nh;
                    bool pt = (P.x[bb*SS_ + w] == 0);
                    float h_old = P.hbuf[(size_t)parity*8192 + cidx];
                    float hn = pt ? h_old : nh;
                    float cn = pt ? c_old : nc;
                    P.cbuf[cidx] = cn;
                    int np = parity ^ 1;
                    P.hbuf[(size_t)np*8192 + cidx] = hn;
                    unsigned short hi_, lo_; splitbf(hn, hi_, lo_);
                    P.hbuf_hi[(size_t)np*8192 + cidx] = hi_;
                    P.hbuf_lo[(size_t)np*8192 + cidx] = lo_;
                }
                __syncthreads();
            }
        }
        gbar(P.bar, (unsigned)(w + 1));
    }
}

// ---------------- host launcher ----------------
extern "C" void kernel_launch(void* const* d_in, const int* in_sizes, int n_in,
                              void* d_out, int out_size, void* d_ws, size_t ws_size,
                              hipStream_t stream)
{
    const int*   x       = (const int*)d_in[0];
    const float* emb     = (const float*)d_in[2];
    const float* W_ih    = (const float*)d_in[3];
    const float* W_hh    = (const float*)d_in[4];
    const float* b_lstm  = (const float*)d_in[5];
    const float* W_write = (const float*)d_in[6];
    const float* b_write = (const float*)d_in[7];
    const float* W_read  = (const float*)d_in[8];
    const float* b_read  = (const float*)d_in[9];
    const float* W_lin   = (const float*)d_in[10];
    const float* b_lin   = (const float*)d_in[11];
    const float* W_out   = (const float*)d_in[12];
    float* out = (float*)d_out;
    char* ws = (char*)d_ws;

    unsigned short* xe_hi   = (unsigned short*)(ws + OFF_XE_HI);
    unsigned short* xe_lo   = (unsigned short*)(ws + OFF_XE_LO);
    unsigned short* wih_hi  = (unsigned short*)(ws + OFF_WIH_HI);
    unsigned short* wih_lo  = (unsigned short*)(ws + OFF_WIH_LO);
    unsigned short* whh_hi  = (unsigned short*)(ws + OFF_WHH_HI);
    unsigned short* whh_lo  = (unsigned short*)(ws + OFF_WHH_LO);
    unsigned short* wout_bf = (unsigned short*)(ws + OFF_WOUT);
    float*          xproj   = (float*)(ws + OFF_XPROJ);
    unsigned short* outs_bf = (unsigned short*)(ws + OFF_OUTSBF);
    float*          hbuf    = (float*)(ws + OFF_HBUF);
    unsigned short* hbuf_hi = (unsigned short*)(ws + OFF_HBUFHI);
    unsigned short* hbuf_lo = (unsigned short*)(ws + OFF_HBUFLO);
    float*          cbuf    = (float*)(ws + OFF_CBUF);
    float*          zbuf    = (float*)(ws + OFF_ZBUF);
    float*          pbuf    = (float*)(ws + OFF_PBUF);
    unsigned*       bar     = (unsigned*)(ws + OFF_BAR);

    hipLaunchKernelGGL(k_prep, dim3(4096), dim3(256), 0, stream,
        x, emb, W_ih, W_hh, W_out,
        xe_hi, xe_lo, wih_hi, wih_lo, whh_hi, whh_lo, wout_bf,
        (unsigned*)(ws + OFF_HBUF));

    hipLaunchKernelGGL(k_xproj, dim3(16, 64), dim3(256), 0, stream,
        xe_hi, xe_lo, wih_hi, wih_lo, b_lstm, xproj);

    RecP P;
    P.xproj = xproj; P.whh_hi = whh_hi; P.whh_lo = whh_lo; P.x = x;
    P.W_write = W_write; P.b_write = b_write; P.W_read = W_read; P.b_read = b_read;
    P.W_lin = W_lin; P.b_lin = b_lin;
    P.outs_bf = outs_bf;
    P.hbuf = hbuf; P.hbuf_hi = hbuf_hi; P.hbuf_lo = hbuf_lo;
    P.cbuf = cbuf; P.zbuf = zbuf; P.pbuf = pbuf;
    P.bar = bar;
    P.fraw_out = out + (size_t)SB * SS_ * SV;
    hipLaunchKernelGGL(k_rec, dim3(NBLK_REC), dim3(256), 0, stream, P);

    hipLaunchKernelGGL(k_logits, dim3(64, 64), dim3(256), 0, stream,
        outs_bf, wout_bf, out);
}

// Round 2
// 5387.767 us; speedup vs baseline: 1.8481x; 1.8481x over previous
//
#include <hip/hip_runtime.h>

// ---------------- types / helpers ----------------
typedef short bf8_t __attribute__((ext_vector_type(8)));   // 8 x bf16
typedef float f4_t  __attribute__((ext_vector_type(4)));

__device__ __forceinline__ f4_t mfma_bf16(bf8_t a, bf8_t b, f4_t c){
    return __builtin_amdgcn_mfma_f32_16x16x32_bf16(a, b, c, 0, 0, 0);
}
__device__ __forceinline__ unsigned short f2bf(float f){
    unsigned u = __float_as_uint(f);
    unsigned r = (u + 0x7FFFu + ((u >> 16) & 1u)) >> 16;
    return (unsigned short)r;
}
__device__ __forceinline__ float bf2f(unsigned short b){
    return __uint_as_float(((unsigned)b) << 16);
}
__device__ __forceinline__ void splitbf(float v, unsigned short& hi, unsigned short& lo){
    hi = f2bf(v);
    lo = f2bf(v - bf2f(hi));
}
__device__ __forceinline__ float sigm(float x){ return 1.0f / (1.0f + expf(-x)); }

// ---------------- problem sizes ----------------
#define SB   16      // batch
#define SS_  512     // seq
#define SH   512     // hidden
#define SE   256     // emb
#define SV   8192    // vocab
#define NBLK_REC 96  // 16 F + 48 proj + 32 gates

// ---------------- workspace layout (bytes) ----------------
#define OFF_XE_HI   ((size_t)0)
#define OFF_XE_LO   ((size_t)4194304)
#define OFF_WIH_HI  ((size_t)8388608)
#define OFF_WIH_LO  ((size_t)9437184)
#define OFF_WHH_HI  ((size_t)10485760)
#define OFF_WHH_LO  ((size_t)12582912)
#define OFF_WOUT    ((size_t)14680064)
#define OFF_XPROJ   ((size_t)23068672)
#define OFF_OUTSBF  ((size_t)90177536)
#define OFF_HBUF    ((size_t)98566144)   // zero region starts here
#define OFF_HBUFHI  ((size_t)98631680)
#define OFF_HBUFLO  ((size_t)98664448)
#define OFF_CBUF    ((size_t)98697216)
#define OFF_ZBUF    ((size_t)98729984)
#define OFF_PBUF    ((size_t)98828288)
#define OFF_BAR     ((size_t)98850816)   // 96 slots x 128B (RMW-free barrier)
#define ZERO_WORDS  77312                // (98875392 - 98566144)/4

// ---------------- prep: conversions + gather + zero ----------------
#define N_WHH  1048576
#define N_WIH  524288
#define N_WOUT 4194304
#define N_XE   2097152
#define N_PREP (N_WHH + N_WIH + N_WOUT + N_XE + ZERO_WORDS)

__global__ __launch_bounds__(256) void k_prep(
    const int* __restrict__ x, const float* __restrict__ emb,
    const float* __restrict__ W_ih, const float* __restrict__ W_hh,
    const float* __restrict__ W_out,
    unsigned short* __restrict__ xe_hi, unsigned short* __restrict__ xe_lo,
    unsigned short* __restrict__ wih_hi, unsigned short* __restrict__ wih_lo,
    unsigned short* __restrict__ whh_hi, unsigned short* __restrict__ whh_lo,
    unsigned short* __restrict__ wout_bf, unsigned* __restrict__ zero_base)
{
    for (long i = (long)blockIdx.x * 256 + threadIdx.x; i < N_PREP; i += (long)gridDim.x * 256){
        long j = i;
        if (j < N_WHH){
            unsigned short h, l; splitbf(W_hh[j], h, l); whh_hi[j] = h; whh_lo[j] = l; continue;
        }
        j -= N_WHH;
        if (j < N_WIH){
            unsigned short h, l; splitbf(W_ih[j], h, l); wih_hi[j] = h; wih_lo[j] = l; continue;
        }
        j -= N_WIH;
        if (j < N_WOUT){ wout_bf[j] = f2bf(W_out[j]); continue; }
        j -= N_WOUT;
        if (j < N_XE){
            int r = (int)(j >> 8), e = (int)(j & 255);
            int t = r >> 4, b = r & 15;
            int tok = x[b * SS_ + t];
            unsigned short h, l; splitbf(emb[(size_t)tok * SE + e], h, l);
            xe_hi[j] = h; xe_lo[j] = l; continue;
        }
        j -= N_XE;
        zero_base[j] = 0u;
    }
}

// ---------------- xproj GEMM: C[8192][2048] = xe(hi/lo) @ W_ih(hi/lo)^T + b ----------------
__global__ __launch_bounds__(256) void k_xproj(
    const unsigned short* __restrict__ Ah, const unsigned short* __restrict__ Al,
    const unsigned short* __restrict__ Bh, const unsigned short* __restrict__ Bl,
    const float* __restrict__ bias, float* __restrict__ C)
{
    constexpr int K = 256, N = 2048;
    __shared__ unsigned short sA0[128*32], sA1[128*32], sB0[128*32], sB1[128*32];
    const int tid = threadIdx.x;
    const int m0 = blockIdx.y * 128, n0 = blockIdx.x * 128;
    const int lane = tid & 63, wid = tid >> 6;
    const int lm = lane & 15, lq = lane >> 4;
    const int wm = wid & 1, wn = wid >> 1;
    f4_t zero4 = {0.f, 0.f, 0.f, 0.f};
    f4_t acc[4][4];
    #pragma unroll
    for (int i = 0; i < 4; ++i)
        #pragma unroll
        for (int j = 0; j < 4; ++j) acc[i][j] = zero4;
    const int srow = tid >> 2, sq = tid & 3;
    for (int kk = 0; kk < K; kk += 32){
        __syncthreads();
        #pragma unroll
        for (int r2 = 0; r2 < 2; ++r2){
            int row = r2 * 64 + srow;
            int cell = (((row >> 4) << 2) + sq) * 16 + (row & 15);
            *(bf8_t*)&sA0[cell*8] = *(const bf8_t*)&Ah[(size_t)(m0+row)*K + kk + sq*8];
            *(bf8_t*)&sA1[cell*8] = *(const bf8_t*)&Al[(size_t)(m0+row)*K + kk + sq*8];
            *(bf8_t*)&sB0[cell*8] = *(const bf8_t*)&Bh[(size_t)(n0+row)*K + kk + sq*8];
            *(bf8_t*)&sB1[cell*8] = *(const bf8_t*)&Bl[(size_t)(n0+row)*K + kk + sq*8];
        }
        __syncthreads();
        bf8_t ah[4], al[4], bh[4], bl[4];
        #pragma unroll
        for (int i = 0; i < 4; ++i){
            int ca = (((wm*4 + i)*4 + lq)*16 + lm)*8;
            ah[i] = *(bf8_t*)&sA0[ca]; al[i] = *(bf8_t*)&sA1[ca];
            int cb = (((wn*4 + i)*4 + lq)*16 + lm)*8;
            bh[i] = *(bf8_t*)&sB0[cb]; bl[i] = *(bf8_t*)&sB1[cb];
        }
        #pragma unroll
        for (int i = 0; i < 4; ++i)
            #pragma unroll
            for (int j = 0; j < 4; ++j){
                acc[i][j] = mfma_bf16(ah[i], bh[j], acc[i][j]);
                acc[i][j] = mfma_bf16(ah[i], bl[j], acc[i][j]);
                acc[i][j] = mfma_bf16(al[i], bh[j], acc[i][j]);
            }
    }
    #pragma unroll
    for (int i = 0; i < 4; ++i)
        #pragma unroll
        for (int j = 0; j < 4; ++j){
            int mg = m0 + (wm*4 + i)*16 + lq*4;
            int ng = n0 + (wn*4 + j)*16 + lm;
            float bn = bias[ng];
            #pragma unroll
            for (int r = 0; r < 4; ++r)
                C[(size_t)(mg + r)*N + ng] = acc[i][j][r] + bn;
        }
}

// ---------------- logits GEMM: C[8192][8192] = outs_bf @ wout_bf^T ----------------
__global__ __launch_bounds__(256) void k_logits(
    const unsigned short* __restrict__ A, const unsigned short* __restrict__ B,
    float* __restrict__ C)
{
    constexpr int K = 512, N = 8192;
    __shared__ unsigned short sA[128*32], sB[128*32];
    const int tid = threadIdx.x;
    const int m0 = blockIdx.y * 128, n0 = blockIdx.x * 128;
    const int lane = tid & 63, wid = tid >> 6;
    const int lm = lane & 15, lq = lane >> 4;
    const int wm = wid & 1, wn = wid >> 1;
    f4_t zero4 = {0.f, 0.f, 0.f, 0.f};
    f4_t acc[4][4];
    #pragma unroll
    for (int i = 0; i < 4; ++i)
        #pragma unroll
        for (int j = 0; j < 4; ++j) acc[i][j] = zero4;
    const int srow = tid >> 2, sq = tid & 3;
    for (int kk = 0; kk < K; kk += 32){
        __syncthreads();
        #pragma unroll
        for (int r2 = 0; r2 < 2; ++r2){
            int row = r2 * 64 + srow;
            int cell = (((row >> 4) << 2) + sq) * 16 + (row & 15);
            *(bf8_t*)&sA[cell*8] = *(const bf8_t*)&A[(size_t)(m0+row)*K + kk + sq*8];
            *(bf8_t*)&sB[cell*8] = *(const bf8_t*)&B[(size_t)(n0+row)*K + kk + sq*8];
        }
        __syncthreads();
        bf8_t af[4], bfv[4];
        #pragma unroll
        for (int i = 0; i < 4; ++i){
            af[i]  = *(bf8_t*)&sA[(((wm*4 + i)*4 + lq)*16 + lm)*8];
            bfv[i] = *(bf8_t*)&sB[(((wn*4 + i)*4 + lq)*16 + lm)*8];
        }
        #pragma unroll
        for (int i = 0; i < 4; ++i)
            #pragma unroll
            for (int j = 0; j < 4; ++j)
                acc[i][j] = mfma_bf16(af[i], bfv[j], acc[i][j]);
    }
    #pragma unroll
    for (int i = 0; i < 4; ++i)
        #pragma unroll
        for (int j = 0; j < 4; ++j){
            int mg = m0 + (wm*4 + i)*16 + lq*4;
            int ng = n0 + (wn*4 + j)*16 + lm;
            #pragma unroll
            for (int r = 0; r < 4; ++r)
                C[(size_t)(mg + r)*N + ng] = acc[i][j][r];
        }
}

// ---------------- persistent recurrent kernel ----------------
struct RecP {
    const float* xproj;
    const unsigned short* whh_hi; const unsigned short* whh_lo;
    const int* x;
    const float* W_write; const float* b_write;
    const float* W_read;  const float* b_read;
    const float* W_lin;   const float* b_lin;
    unsigned short* outs_bf;
    float* hbuf; unsigned short* hbuf_hi; unsigned short* hbuf_lo;
    float* cbuf; float* zbuf; float* pbuf;
    unsigned* bar;
    float* fraw_out;
};

// RMW-free distributed barrier: block b release-stores epoch to its own
// 128B slot; wave 0 of every block polls all 96 slots (lane i -> slot i)
// with RELAXED agent loads; single fence on exit. No same-line atomics.
#define BAR_W 32
__device__ __forceinline__ void gbar(unsigned* bar, int bid, unsigned epoch){
    __syncthreads();
    if (threadIdx.x == 0){
        __threadfence();
        __hip_atomic_store(&bar[BAR_W*bid], epoch, __ATOMIC_RELAXED, __HIP_MEMORY_SCOPE_AGENT);
    }
    if (threadIdx.x < 64){
        int i0 = threadIdx.x, i1 = threadIdx.x + 64;
        unsigned v0 = 0u, v1 = (i1 < NBLK_REC) ? 0u : epoch;
        for (;;){
            if (v0 < epoch) v0 = __hip_atomic_load(&bar[BAR_W*i0], __ATOMIC_RELAXED, __HIP_MEMORY_SCOPE_AGENT);
            if (v1 < epoch) v1 = __hip_atomic_load(&bar[BAR_W*i1], __ATOMIC_RELAXED, __HIP_MEMORY_SCOPE_AGENT);
            if (__all((v0 >= epoch) && (v1 >= epoch))) break;
            __builtin_amdgcn_s_sleep(1);
        }
        if (threadIdx.x == 0) __threadfence();
    }
    __syncthreads();
}

// shared-mem float offsets (union across roles)
// F: wsr@0[1024] qrr@1024[1024] scr@2048[1152] sv@3200 rv@3232 tv@3264 qv@3296
//    rrv@3328 nvg@3360 qn@3392 red@3424[8] msc@3432[8] wlin(bf16)@4096[8192 floats]
// proj: zt(cells)@0[8192] wlds@8192[4*516] scratch@10256[256] bias@10512[4]
// gates: gsc@0[4*16*17]
__global__ void __launch_bounds__(256, 1) k_rec(RecP P)
{
    __shared__ __align__(16) float smem[12288];
    const int tid = threadIdx.x, bid = blockIdx.x;
    const int lane = tid & 63, wv = tid >> 6;
    const int lm = lane & 15, lq = lane >> 4;
    f4_t zero4 = {0.f, 0.f, 0.f, 0.f};

    f4_t Freg[32];
    #pragma unroll
    for (int i = 0; i < 32; ++i) Freg[i] = zero4;

    // persistent W_hh registers + xproj prefetch (gates blocks only)
    bf8_t wbh[16], wbl[16];
    float xpr[4];
    const int h0g = (bid - 64) * 16;

    // one-time per-block init
    if (bid < 16){
        if (tid == 0) smem[3432] = 1.0f;         // g scalar
        unsigned short* wlin = (unsigned short*)&smem[4096];
        for (int i = tid; i < 16384; i += 256) wlin[i] = f2bf(P.W_lin[i]);
    } else if (bid < 64){
        int pj = bid - 16;
        for (int i = tid; i < 4*512; i += 256){
            int rl = i >> 9, k = i & 511;
            int jr = pj*4 + rl;
            float v = 0.f;
            if (jr < 97) v = P.W_write[jr*512 + k];
            else if (jr < 161) v = P.W_read[(jr-97)*512 + k];
            smem[8192 + rl*516 + k] = v;
        }
        if (tid < 4){
            int jr = pj*4 + tid;
            float v = 0.f;
            if (jr < 97) v = P.b_write[jr];
            else if (jr < 161) v = P.b_read[jr-97];
            smem[10512 + tid] = v;
        }
    } else {
        // pin this block's W_hh slice (hi/lo) in VGPRs for the whole loop
        const unsigned short* bh = P.whh_hi + (size_t)(wv*512 + h0g + lm)*512;
        const unsigned short* bl = P.whh_lo + (size_t)(wv*512 + h0g + lm)*512;
        #pragma unroll
        for (int kc = 0; kc < 16; ++kc){
            int k = kc*32 + lq*8;
            wbh[kc] = *(const bf8_t*)(bh + k);
            wbl[kc] = *(const bf8_t*)(bl + k);
        }
        #pragma unroll
        for (int r = 0; r < 4; ++r){
            int m = lq*4 + r;
            xpr[r] = P.xproj[(size_t)(0*16 + m)*2048 + wv*512 + h0g + lm];
        }
    }
    __syncthreads();

    for (int w = 0; w < SS_ + 2; ++w){
        if (bid < 16){
            // ---------------- F block: batch b, step wf = w-2 ----------------
            if (w >= 2){
                const int b = bid, wf = w - 2;
                float* wsr = smem;        float* qrr = smem + 1024;
                float* scr = smem + 2048; float* sv  = smem + 3200;
                float* rv_ = smem + 3232; float* tv  = smem + 3264;
                float* qv_ = smem + 3296; float* rrv = smem + 3328;
                float* nvg = smem + 3360; float* qn  = smem + 3392;
                float* red = smem + 3424; float* msc = smem + 3432;
                const float* prow = P.pbuf + (size_t)(wf & 1)*(16*176) + b*176;
                if (tid < 161){
                    float val = prow[tid];
                    if (tid < 32) sv[tid] = val;
                    else if (tid < 64) rv_[tid-32] = val;
                    else if (tid < 96) tv[tid-64] = val;
                    else if (tid < 128) qv_[tid-96] = val;
                    else if (tid < 160) rrv[tid-128] = val;
                    else msc[1] = val;                         // beta
                }
                if (tid == 161) msc[3] = (P.x[b*SS_ + wf] == 0) ? 1.0f : 0.0f;
                __syncthreads();
                #pragma unroll
                for (int p = tid; p < 1024; p += 256){
                    int si = p >> 5, ri = p & 31;
                    wsr[p] = sv[si] * rv_[ri];
                    qrr[p] = qv_[si] * rrv[ri];
                }
                __syncthreads();
                const int tsg = lane & 7, p0 = lane >> 3;
                const int pb = wv*256 + p0;
                // pass A: v einsum
                f4_t vacc = zero4;
                #pragma unroll
                for (int it = 0; it < 32; ++it)
                    vacc += Freg[it] * wsr[pb + it*8];
                *(f4_t*)&scr[(wv*8 + p0)*36 + tsg*4] = vacc;
                __syncthreads();
                float gcur = msc[0];
                float beta = msc[1];
                if (tid < 32){
                    float ve = 0.f;
                    #pragma unroll
                    for (int r = 0; r < 32; ++r) ve += scr[r*36 + tid];
                    float nv = beta * (tv[tid] - gcur * ve) * (1.0f/32.0f);
                    nvg[tid] = nv / gcur;
                }
                __syncthreads();
                // pass B: fn, norm acc, q acc, F update
                f4_t nv4 = *(const f4_t*)&nvg[tsg*4];
                bool upd = (msc[3] == 0.0f);
                float nacc = 0.f; f4_t qacc = zero4;
                #pragma unroll
                for (int it = 0; it < 32; ++it){
                    int p = pb + it*8;
                    f4_t fn = Freg[it] + wsr[p] * nv4;
                    nacc += fn[0]*fn[0] + fn[1]*fn[1] + fn[2]*fn[2] + fn[3]*fn[3];
                    qacc += fn * qrr[p];
                    if (upd) Freg[it] = fn;
                }
                *(f4_t*)&scr[(wv*8 + p0)*36 + tsg*4] = qacc;
                #pragma unroll
                for (int off = 32; off > 0; off >>= 1) nacc += __shfl_down(nacc, off);
                if (lane == 0) red[wv] = nacc;
                __syncthreads();
                if (tid == 0){
                    float tot = red[0] + red[1] + red[2] + red[3];
                    float fraw = gcur * sqrtf(tot);
                    msc[2] = fraw;
                    float ex = fraw - 1.0f; if (ex < 0.f) ex = 0.f;
                    if (upd) msc[0] = gcur / (ex + 1.0f);
                }
                __syncthreads();
                if (tid < 32){
                    float q_ = 0.f;
                    #pragma unroll
                    for (int r = 0; r < 32; ++r) q_ += scr[r*36 + tid];
                    float mu = q_;
                    mu += __shfl_xor(mu, 1);  mu += __shfl_xor(mu, 2);
                    mu += __shfl_xor(mu, 4);  mu += __shfl_xor(mu, 8);
                    mu += __shfl_xor(mu, 16); mu *= (1.0f/32.0f);
                    float d = q_ - mu;
                    float vvr = d * d;
                    vvr += __shfl_xor(vvr, 1);  vvr += __shfl_xor(vvr, 2);
                    vvr += __shfl_xor(vvr, 4);  vvr += __shfl_xor(vvr, 8);
                    vvr += __shfl_xor(vvr, 16); vvr *= (1.0f/32.0f);
                    qn[tid] = d / sqrtf(vvr + 1e-5f);
                }
                __syncthreads();
                const float* zrow = P.zbuf + (size_t)(wf % 3)*8192 + b*512;
                f4_t qn4[8];
                #pragma unroll
                for (int i = 0; i < 8; ++i) qn4[i] = ((const f4_t*)qn)[i];
                const unsigned short* wlin = (const unsigned short*)&smem[4096];
                for (int h = tid; h < 512; h += 256){
                    const bf8_t* wl8 = (const bf8_t*)(wlin + h*32);
                    float o = P.b_lin[h] + zrow[h];
                    #pragma unroll
                    for (int i = 0; i < 4; ++i){
                        bf8_t wv8 = wl8[i];
                        #pragma unroll
                        for (int j = 0; j < 8; ++j){
                            int idx = i*8 + j;
                            o += bf2f((unsigned short)wv8[j]) * qn4[idx >> 2][idx & 3];
                        }
                    }
                    P.outs_bf[(size_t)(b*SS_ + wf)*SH + h] = f2bf(o);
                }
                if (wf == SS_ - 1 && tid == 0) P.fraw_out[b] = msc[2];
            }
        } else if (bid < 64){
            // ---------------- proj block: rows pj*4..+3, step wp = w-1 ----------------
            if (w >= 1 && w <= SS_){
                const int pj = bid - 16, wp = w - 1;
                const float* zsrc = P.zbuf + (size_t)(wp % 3)*8192;
                for (int c = tid; c < 2048; c += 256){
                    int i = c >> 6, bb = (c >> 2) & 15, hf = c & 3;
                    ((f4_t*)smem)[c] = *(const f4_t*)&zsrc[bb*512 + (hf + 4*i)*4];
                }
                __syncthreads();
                {
                    int rl = tid >> 6, bb = (tid >> 2) & 15, hf = tid & 3;
                    float acc = 0.f;
                    #pragma unroll 4
                    for (int i = 0; i < 32; ++i){
                        f4_t z4 = ((f4_t*)smem)[i*64 + bb*4 + hf];
                        f4_t w4 = *(f4_t*)&smem[8192 + rl*516 + (hf + 4*i)*4];
                        acc += z4[0]*w4[0] + z4[1]*w4[1] + z4[2]*w4[2] + z4[3]*w4[3];
                    }
                    smem[10256 + tid] = acc;
                }
                __syncthreads();
                if (tid < 64){
                    int rl = tid >> 4, bb = tid & 15;
                    int base = 10256 + rl*64 + bb*4;
                    float v = smem[base] + smem[base+1] + smem[base+2] + smem[base+3]
                            + smem[10512 + rl];
                    int jr = pj*4 + rl;
                    float* pbrow = P.pbuf + (size_t)(wp & 1)*(16*176) + bb*176;
                    if (jr < 32)        pbrow[jr] = tanhf(v);
                    else if (jr < 64)   pbrow[jr] = tanhf(v);
                    else if (jr < 96)   pbrow[jr] = tanhf(v);
                    else if (jr == 96)  pbrow[160] = sigm(v + 1.0f);
                    else if (jr < 129)  pbrow[96 + (jr - 97)] = v;
                    else if (jr < 161)  pbrow[128 + (jr - 129)] = tanhf(v);
                }
                __syncthreads();
            }
        } else {
            // ---------------- gates block: h0..h0+15, step w ----------------
            if (w < SS_){
                const int parity = w & 1;
                const int g = wv;   // wave = gate
                const unsigned short* ah = P.hbuf_hi + (size_t)parity*8192 + lm*512;
                const unsigned short* al = P.hbuf_lo + (size_t)parity*8192 + lm*512;
                f4_t accs[4];
                #pragma unroll
                for (int i = 0; i < 4; ++i) accs[i] = zero4;
                #pragma unroll
                for (int kc = 0; kc < 16; ++kc){
                    int k = kc*32 + lq*8;
                    bf8_t vah = *(const bf8_t*)(ah + k);
                    bf8_t val_ = *(const bf8_t*)(al + k);
                    accs[kc & 3] = mfma_bf16(vah, wbh[kc], accs[kc & 3]);
                    accs[kc & 3] = mfma_bf16(vah, wbl[kc], accs[kc & 3]);
                    accs[kc & 3] = mfma_bf16(val_, wbh[kc], accs[kc & 3]);
                }
                f4_t s4 = accs[0] + accs[1] + accs[2] + accs[3];
                #pragma unroll
                for (int r = 0; r < 4; ++r){
                    int m = lq*4 + r;
                    smem[(g*16 + m)*17 + lm] = s4[r] + xpr[r];
                }
                __syncthreads();
                {
                    int bb = tid >> 4, hh = tid & 15, h = h0g + hh;
                    float iv = smem[(0*16 + bb)*17 + hh];
                    float fv = smem[(1*16 + bb)*17 + hh];
                    float zg = smem[(2*16 + bb)*17 + hh];
                    float ov = smem[(3*16 + bb)*17 + hh];
                    iv = sigm(iv); fv = sigm(fv + 1.0f); zg = tanhf(zg); ov = sigm(ov);
                    int cidx = bb*512 + h;
                    float c_old = P.cbuf[cidx];
                    float nc = fv * c_old + iv * zg;
                    float nh = ov * tanhf(nc);
                    P.zbuf[(size_t)(w % 3)*8192 + cidx] = nh;
                    bool pt = (P.x[bb*SS_ + w] == 0);
                    float h_old = P.hbuf[(size_t)parity*8192 + cidx];
                    float hn = pt ? h_old : nh;
                    float cn = pt ? c_old : nc;
                    P.cbuf[cidx] = cn;
                    int np = parity ^ 1;
                    P.hbuf[(size_t)np*8192 + cidx] = hn;
                    unsigned short hi_, lo_; splitbf(hn, hi_, lo_);
                    P.hbuf_hi[(size_t)np*8192 + cidx] = hi_;
                    P.hbuf_lo[(size_t)np*8192 + cidx] = lo_;
                }
                // prefetch next step's xproj fragment (independent of barrier)
                if (w + 1 < SS_){
                    #pragma unroll
                    for (int r = 0; r < 4; ++r){
                        int m = lq*4 + r;
                        xpr[r] = P.xproj[(size_t)((w+1)*16 + m)*2048 + g*512 + h0g + lm];
                    }
                }
            }
        }
        gbar(P.bar, bid, (unsigned)(w + 1));
    }
}

// ---------------- host launcher ----------------
extern "C" void kernel_launch(void* const* d_in, const int* in_sizes, int n_in,
                              void* d_out, int out_size, void* d_ws, size_t ws_size,
                              hipStream_t stream)
{
    const int*   x       = (const int*)d_in[0];
    const float* emb     = (const float*)d_in[2];
    const float* W_ih    = (const float*)d_in[3];
    const float* W_hh    = (const float*)d_in[4];
    const float* b_lstm  = (const float*)d_in[5];
    const float* W_write = (const float*)d_in[6];
    const float* b_write = (const float*)d_in[7];
    const float* W_read  = (const float*)d_in[8];
    const float* b_read  = (const float*)d_in[9];
    const float* W_lin   = (const float*)d_in[10];
    const float* b_lin   = (const float*)d_in[11];
    const float* W_out   = (const float*)d_in[12];
    float* out = (float*)d_out;
    char* ws = (char*)d_ws;

    unsigned short* xe_hi   = (unsigned short*)(ws + OFF_XE_HI);
    unsigned short* xe_lo   = (unsigned short*)(ws + OFF_XE_LO);
    unsigned short* wih_hi  = (unsigned short*)(ws + OFF_WIH_HI);
    unsigned short* wih_lo  = (unsigned short*)(ws + OFF_WIH_LO);
    unsigned short* whh_hi  = (unsigned short*)(ws + OFF_WHH_HI);
    unsigned short* whh_lo  = (unsigned short*)(ws + OFF_WHH_LO);
    unsigned short* wout_bf = (unsigned short*)(ws + OFF_WOUT);
    float*          xproj   = (float*)(ws + OFF_XPROJ);
    unsigned short* outs_bf = (unsigned short*)(ws + OFF_OUTSBF);
    float*          hbuf    = (float*)(ws + OFF_HBUF);
    unsigned short* hbuf_hi = (unsigned short*)(ws + OFF_HBUFHI);
    unsigned short* hbuf_lo = (unsigned short*)(ws + OFF_HBUFLO);
    float*          cbuf    = (float*)(ws + OFF_CBUF);
    float*          zbuf    = (float*)(ws + OFF_ZBUF);
    float*          pbuf    = (float*)(ws + OFF_PBUF);
    unsigned*       bar     = (unsigned*)(ws + OFF_BAR);

    hipLaunchKernelGGL(k_prep, dim3(4096), dim3(256), 0, stream,
        x, emb, W_ih, W_hh, W_out,
        xe_hi, xe_lo, wih_hi, wih_lo, whh_hi, whh_lo, wout_bf,
        (unsigned*)(ws + OFF_HBUF));

    hipLaunchKernelGGL(k_xproj, dim3(16, 64), dim3(256), 0, stream,
        xe_hi, xe_lo, wih_hi, wih_lo, b_lstm, xproj);

    RecP P;
    P.xproj = xproj; P.whh_hi = whh_hi; P.whh_lo = whh_lo; P.x = x;
    P.W_write = W_write; P.b_write = b_write; P.W_read = W_read; P.b_read = b_read;
    P.W_lin = W_lin; P.b_lin = b_lin;
    P.outs_bf = outs_bf;
    P.hbuf = hbuf; P.hbuf_hi = hbuf_hi; P.hbuf_lo = hbuf_lo;
    P.cbuf = cbuf; P.zbuf = zbuf; P.pbuf = pbuf;
    P.bar = bar;
    P.fraw_out = out + (size_t)SB * SS_ * SV;
    hipLaunchKernelGGL(k_rec, dim3(NBLK_REC), dim3(256), 0, stream, P);

    hipLaunchKernelGGL(k_logits, dim3(64, 64), dim3(256), 0, stream,
        outs_bf, wout_bf, out);
}